// Round 3
// baseline (28.794 us; speedup 1.0000x reference)
//
#include <hip/hip_runtime.h>

#define N_PART 512
#define H_DIM 32
#define M_DIM 4
#define L_DIM 8
#define N_STEPS (M_DIM * (L_DIM - 1))   // 28
#define N_JOBS (N_STEPS + M_DIM)        // 32
#define NBLK (N_JOBS * 32)              // 1024 (32 rowgroups of 16 rows)
#define NCELL 2048
#define RMAX 10.0f
#define TSCALE ((float)NCELL / RMAX)    // 204.8
#define TWO_LOG2E 2.8853900817779268f

// ws layout:
//  [0, 8KB)      stTab  float[2048]   (Phi value table)
//  [8KB, 24KB)   gsTab  float2[2048]  ({dPhi, d2Phi} table)
//  [24KB, 48KB)  partials double[1024][3]
//  [48KB, +4)    ticket  unsigned
#define ST_BYTES (NCELL * 4)
#define GS_BYTES (NCELL * 8)
#define PART_OFF (ST_BYTES + GS_BYTES)
#define PART_BYTES (NBLK * 3 * 8)
#define TICKET_OFF (PART_OFF + PART_BYTES)

// ---------------------------------------------------------------------------
// Build the r-tables: cell c holds St (Phi) and {Sg,Sl} ({dPhi,d2Phi}) at
// r = c/TSCALE. Also zeroes the ticket used by the fused last-block finalize.
__global__ __launch_bounds__(256)
void tfl_tabgen(const float* __restrict__ p1, const float* __restrict__ pb1,
                const float* __restrict__ p2, float* __restrict__ stTab,
                float2* __restrict__ gsTab, unsigned* __restrict__ ticket) {
  if (blockIdx.x == 0 && threadIdx.x == 0) *ticket = 0u;
  const int c = blockIdx.x * 256 + threadIdx.x;
  if (c >= NCELL) return;
  const float r = (float)c * (RMAX / (float)NCELL);
  float St = 0.f, Sg = 0.f, Sl = 0.f;
  for (int h = 0; h < H_DIM; ++h) {
    float p1h = p1[h], P2h = p2[h];
    float arg = TWO_LOG2E * fmaf(r, p1h, pb1[h]);
    float y = __builtin_amdgcn_exp2f(arg);
    float u = __builtin_amdgcn_rcpf(y + 1.0f);
    float t = fmaf(-2.0f, u, 1.0f);            // tanh
    float dd = fmaf(-u, u, u);                 // sech^2 / 4
    St = fmaf(t, P2h, St);
    Sg = fmaf(dd, 4.0f * p1h * P2h, Sg);       // dPhi
    Sl = fmaf(t * dd, -8.0f * p1h * p1h * P2h, Sl);  // d2Phi
  }
  stTab[c] = St;
  gsTab[c] = make_float2(Sg, Sl);
}

// ---------------------------------------------------------------------------
// Main: 1024 blocks = 32 jobs x 32 rowgroups(16 rows). 512 threads:
// 32 threads per row, each thread owns 16 j's.
// Mode-specialized (E is telescoped, so only l==0 / l==7 need St & V-value):
//   DRIFT (l=1..6, 24 jobs): gather b64 {Sg,Sl} only; skip St and Vi.
//   L0    (l==0,   4 jobs): gather b64 + b32 St; everything.
//   EMODE (l==7,   4 jobs): gather b32 St only; skip drift/laplacian.
// Fused finalize: per-block single-lane relaxed agent stores + RELEASE-scoped
// ticket fetch_add; ONE acquire fence in the winning block. (Round-1 lesson:
// per-wave seq_cst fences emit buffer_inv -> L2 invalidation storm, 145 us.
// Single-lane release = wbl2 only, no invalidates, no storm. No spin-waits,
// so rocprof counter-replay without tabgen cannot hang.)
__global__ __launch_bounds__(512, 8)
void tfl_main7(const float* __restrict__ data, const float* __restrict__ tsnap,
               const float* __restrict__ W1, const float* __restrict__ b1,
               const float* __restrict__ w2, const float* __restrict__ stTab,
               const float2* __restrict__ gsTab, double* partials,
               unsigned* ticket, float* __restrict__ out) {
  const int jb = blockIdx.x >> 5;
  const int rb = blockIdx.x & 31;
  const bool emode = (jb >= N_STEPS);
  const int m = emode ? (jb - N_STEPS) : jb / (L_DIM - 1);
  const int l = emode ? (L_DIM - 1) : jb % (L_DIM - 1);
  const bool l0 = (!emode && l == 0);
  const float* X = data + (size_t)(m * L_DIM + l) * (N_PART * 2);

  __shared__ __align__(16) float sSt[NCELL];    // 8 KB
  __shared__ __align__(16) float2 sGs[NCELL];   // 16 KB
  __shared__ __align__(16) float Xs[N_PART * 2];// 4 KB
  __shared__ double sred[8][3];
  __shared__ unsigned sticket;

  const int tid = threadIdx.x;
  if (tid < 256) ((float4*)Xs)[tid] = ((const float4*)X)[tid];
  if (!emode) {          // DRIFT & L0 need {Sg,Sl}
    ((float4*)sGs)[tid] = ((const float4*)gsTab)[tid];
    ((float4*)sGs)[tid + 512] = ((const float4*)gsTab)[tid + 512];
  }
  if (emode || l0) {     // EMODE & L0 need St
    ((float4*)sSt)[tid] = ((const float4*)stTab)[tid];
  }
  __syncthreads();

  const int wv = tid >> 6;
  const int ln = tid & 63;
  const int g = ln & 31;               // j-group id / h id (32 lanes per row)
  const int row = rb * 16 + (tid >> 5);
  const float xi0 = Xs[2 * row], xi1 = Xs[2 * row + 1];
  const float invN = 1.0f / N_PART;
  const float invN2 = invN * invN;
  const float rs0 = __builtin_amdgcn_rsqf(1e-20f);
  const float2* Xs2 = (const float2*)Xs;

  float bJd = 0.f, bLap = 0.f, bE = 0.f;       // this wave's 2-row partials

  if (!emode && !l0) {
    // ---------------- DRIFT mode: b64 gather, no St, no Vi ----------------
    float aGx = 0.f, aGy = 0.f, aLw = 0.f;
#pragma unroll 8
    for (int kk = 0; kk < 16; ++kk) {
      const int j = g + 32 * kk;
      float2 xj = Xs2[j];
      float dx = xi0 - xj.x, dy = xi1 - xj.y;
      float sq = fmaxf(fmaf(dx, dx, dy * dy), 1e-20f);
      float rs = __builtin_amdgcn_rsqf(sq);
      float r = sq * rs;
      int ki = (int)fmaf(r, TSCALE, 0.5f);
      ki = min(ki, NCELL - 1);
      float2 gs = sGs[ki];
      float tg = gs.x * rs;                     // dPhi / r
      aGx = fmaf(dx, tg, aGx);
      aGy = fmaf(dy, tg, aGy);
      aLw += tg + gs.y;                         // d2Phi + dPhi/r (incl diag)
    }
    // V gradient + laplacian (no Vi needed)
    float gVx, gVy, lapV;
    {
      float w10 = W1[g], w11 = W1[H_DIM + g], w2h = w2[g];
      float arg = TWO_LOG2E * fmaf(xi0, w10, fmaf(xi1, w11, b1[g]));
      float y = __builtin_amdgcn_exp2f(arg);
      float u = __builtin_amdgcn_rcpf(y + 1.0f);
      float t = fmaf(-2.0f, u, 1.0f);
      float dd = fmaf(-u, u, u);
      float g4 = 4.0f * dd * w2h;
      gVx = g4 * w10;
      gVy = g4 * w11;
      lapV = t * dd * (-8.0f * w2h) * fmaf(w10, w10, w11 * w11);
    }
    float gx = fmaf(aGx, invN, gVx);
    float gy = fmaf(aGy, invN, gVy);
    float lw = fmaf(aLw, invN, lapV);
#pragma unroll
    for (int sh = 1; sh < 32; sh <<= 1) {
      gx += __shfl_xor(gx, sh);
      gy += __shfl_xor(gy, sh);
      lw += __shfl_xor(lw, sh);
    }
    float2 gs0 = sGs[0];
    lw -= fmaf(gs0.x, rs0, gs0.y) * invN;       // remove diagonal lap term
    float cJd = fmaf(gx, gx, gy * gy);
    cJd += __shfl_xor(cJd, 32);
    lw += __shfl_xor(lw, 32);
    bJd = cJd; bLap = lw;
  } else if (l0) {
    // ---------------- L0 mode: full (drift + lap + E) ----------------
    float aGx = 0.f, aGy = 0.f, aLw = 0.f, aSt = 0.f;
#pragma unroll 8
    for (int kk = 0; kk < 16; ++kk) {
      const int j = g + 32 * kk;
      float2 xj = Xs2[j];
      float dx = xi0 - xj.x, dy = xi1 - xj.y;
      float sq = fmaxf(fmaf(dx, dx, dy * dy), 1e-20f);
      float rs = __builtin_amdgcn_rsqf(sq);
      float r = sq * rs;
      int ki = (int)fmaf(r, TSCALE, 0.5f);
      ki = min(ki, NCELL - 1);
      float2 gs = sGs[ki];
      float Stv = sSt[ki];
      float tg = gs.x * rs;
      aSt += Stv;
      aGx = fmaf(dx, tg, aGx);
      aGy = fmaf(dy, tg, aGy);
      aLw += tg + gs.y;
    }
    float Vi, gVx, gVy, lapV;
    {
      float w10 = W1[g], w11 = W1[H_DIM + g], w2h = w2[g];
      float arg = TWO_LOG2E * fmaf(xi0, w10, fmaf(xi1, w11, b1[g]));
      float y = __builtin_amdgcn_exp2f(arg);
      float u = __builtin_amdgcn_rcpf(y + 1.0f);
      float t = fmaf(-2.0f, u, 1.0f);
      float dd = fmaf(-u, u, u);
      Vi = t * w2h;
      float g4 = 4.0f * dd * w2h;
      gVx = g4 * w10;
      gVy = g4 * w11;
      lapV = t * dd * (-8.0f * w2h) * fmaf(w10, w10, w11 * w11);
    }
    float eA = fmaf(aSt, invN2, Vi * invN);
    float gx = fmaf(aGx, invN, gVx);
    float gy = fmaf(aGy, invN, gVy);
    float lw = fmaf(aLw, invN, lapV);
#pragma unroll
    for (int sh = 1; sh < 32; sh <<= 1) {
      eA += __shfl_xor(eA, sh);
      gx += __shfl_xor(gx, sh);
      gy += __shfl_xor(gy, sh);
      lw += __shfl_xor(lw, sh);
    }
    float2 gs0 = sGs[0];
    eA -= sSt[0] * invN2;
    lw -= fmaf(gs0.x, rs0, gs0.y) * invN;
    float cJd = fmaf(gx, gx, gy * gy);
    cJd += __shfl_xor(cJd, 32);
    lw += __shfl_xor(lw, 32);
    eA += __shfl_xor(eA, 32);
    bJd = cJd; bLap = lw; bE = eA;
  } else {
    // ---------------- EMODE: b32 St gather only ----------------
    float aSt = 0.f;
#pragma unroll 8
    for (int kk = 0; kk < 16; ++kk) {
      const int j = g + 32 * kk;
      float2 xj = Xs2[j];
      float dx = xi0 - xj.x, dy = xi1 - xj.y;
      float sq = fmaxf(fmaf(dx, dx, dy * dy), 1e-20f);
      float rs = __builtin_amdgcn_rsqf(sq);
      float r = sq * rs;
      int ki = (int)fmaf(r, TSCALE, 0.5f);
      ki = min(ki, NCELL - 1);
      aSt += sSt[ki];
    }
    float Vi;
    {
      float w10 = W1[g], w11 = W1[H_DIM + g], w2h = w2[g];
      float arg = TWO_LOG2E * fmaf(xi0, w10, fmaf(xi1, w11, b1[g]));
      float y = __builtin_amdgcn_exp2f(arg);
      float u = __builtin_amdgcn_rcpf(y + 1.0f);
      float t = fmaf(-2.0f, u, 1.0f);
      Vi = t * w2h;
    }
    float eA = fmaf(aSt, invN2, Vi * invN);
#pragma unroll
    for (int sh = 1; sh < 32; sh <<= 1) eA += __shfl_xor(eA, sh);
    eA -= sSt[0] * invN2;                       // remove diagonal Phi term
    eA += __shfl_xor(eA, 32);
    bE = eA;
  }

  // ----- per-wave partials -> block partial -> global + ticket -----
  if (ln == 0) { sred[wv][0] = bJd; sred[wv][1] = bLap; sred[wv][2] = bE; }
  __syncthreads();
  if (tid == 0) {
    double sJd = 0, sLap = 0, sE = 0;
    for (int w = 0; w < 8; ++w) {
      sJd += sred[w][0]; sLap += sred[w][1]; sE += sred[w][2];
    }
    const double dN = 1.0 / N_PART;
    double j0 = 0.0, j1 = 0.0, j2 = 0.0;
    if (emode) {
      j2 = sE;                                  // +E(m, L-1) telescoped
    } else {
      double dt = (double)(tsnap[l + 1] - tsnap[l]);
      j0 = dt * dN * sJd;                       // J_diss partial
      j1 = dt * 0.01 * dN * sLap;               // J_diff partial
      if (l == 0) j2 = -sE;                     // -E(m, 0) telescoped
    }
    double* myp = partials + (size_t)blockIdx.x * 3;
    __hip_atomic_store(myp + 0, j0, __ATOMIC_RELAXED, __HIP_MEMORY_SCOPE_AGENT);
    __hip_atomic_store(myp + 1, j1, __ATOMIC_RELAXED, __HIP_MEMORY_SCOPE_AGENT);
    __hip_atomic_store(myp + 2, j2, __ATOMIC_RELAXED, __HIP_MEMORY_SCOPE_AGENT);
    // RELEASE orders the three stores before the ticket bump (single-lane
    // wbl2, NO invalidate -> no round-1 cache storm)
    sticket = __hip_atomic_fetch_add(ticket, 1u, __ATOMIC_RELEASE,
                                     __HIP_MEMORY_SCOPE_AGENT);
  }
  __syncthreads();

  // ----- last block to arrive performs the final reduce -----
  if (sticket == NBLK - 1) {
    __builtin_amdgcn_fence(__ATOMIC_ACQUIRE, "agent");  // one acquire, once
    double* pa = partials + (size_t)tid * 3;
    double* pb = partials + (size_t)(tid + 512) * 3;
    double t0 = __hip_atomic_load(pa + 0, __ATOMIC_RELAXED, __HIP_MEMORY_SCOPE_AGENT)
              + __hip_atomic_load(pb + 0, __ATOMIC_RELAXED, __HIP_MEMORY_SCOPE_AGENT);
    double t1 = __hip_atomic_load(pa + 1, __ATOMIC_RELAXED, __HIP_MEMORY_SCOPE_AGENT)
              + __hip_atomic_load(pb + 1, __ATOMIC_RELAXED, __HIP_MEMORY_SCOPE_AGENT);
    double t2 = __hip_atomic_load(pa + 2, __ATOMIC_RELAXED, __HIP_MEMORY_SCOPE_AGENT)
              + __hip_atomic_load(pb + 2, __ATOMIC_RELAXED, __HIP_MEMORY_SCOPE_AGENT);
#pragma unroll
    for (int sh = 1; sh < 64; sh <<= 1) {
      t0 += __shfl_xor(t0, sh);
      t1 += __shfl_xor(t1, sh);
      t2 += __shfl_xor(t2, sh);
    }
    if (ln == 0) { sred[wv][0] = t0; sred[wv][1] = t1; sred[wv][2] = t2; }
    __syncthreads();
    if (tid == 0) {
      double s0 = 0, s1 = 0, s2 = 0;
      for (int w = 0; w < 8; ++w) {
        s0 += sred[w][0]; s1 += sred[w][1]; s2 += sred[w][2];
      }
      double r = (s0 + s1 - 2.0 * s2) / (double)N_STEPS;
      out[0] = (float)(r * r);
    }
  }
}

// ---------------------------------------------------------------------------
extern "C" void kernel_launch(void* const* d_in, const int* in_sizes, int n_in,
                              void* d_out, int out_size, void* d_ws, size_t ws_size,
                              hipStream_t stream) {
  (void)in_sizes; (void)n_in; (void)out_size; (void)ws_size;
  const float* data  = (const float*)d_in[0];
  const float* tsnap = (const float*)d_in[1];
  const float* W1    = (const float*)d_in[2];
  const float* b1    = (const float*)d_in[3];
  const float* w2    = (const float*)d_in[4];
  // d_in[5] = b2 (cancels in telescoped dE)
  const float* p1    = (const float*)d_in[6];
  const float* pb1   = (const float*)d_in[7];
  const float* p2    = (const float*)d_in[8];
  // d_in[9] = pb2 (cancels in telescoped dE)
  float* stTab = (float*)d_ws;
  float2* gsTab = (float2*)((char*)d_ws + ST_BYTES);
  double* partials = (double*)((char*)d_ws + PART_OFF);
  unsigned* ticket = (unsigned*)((char*)d_ws + TICKET_OFF);
  float* out = (float*)d_out;

  hipLaunchKernelGGL(tfl_tabgen, dim3(NCELL / 256), dim3(256), 0, stream,
                     p1, pb1, p2, stTab, gsTab, ticket);
  hipLaunchKernelGGL(tfl_main7, dim3(NBLK), dim3(512), 0, stream,
                     data, tsnap, W1, b1, w2, stTab, gsTab, partials, ticket, out);
}

// Round 4
// 20.889 us; speedup vs baseline: 1.3784x; 1.3784x over previous
//
#include <hip/hip_runtime.h>

#define N_PART 512
#define H_DIM 32
#define M_DIM 4
#define L_DIM 8
#define N_STEPS (M_DIM * (L_DIM - 1))   // 28
#define N_JOBS (N_STEPS + M_DIM)        // 32
#define NBLK (N_JOBS * 32)              // 1024 (32 rowgroups of 16 rows)
#define NCELL 2048
#define RMAX 10.0f
#define TSCALE ((float)NCELL / RMAX)    // 204.8
#define TWO_LOG2E 2.8853900817779268f

// ws layout:
//  [0, 24KB)    tab    float3[2048] {St,Sg,Sl}  (12B stride: full bank spread)
//  [24KB, 32KB) stTab  float[2048]  (packed St for EMODE's 8KB staging)
//  [32KB, 56KB) partials double[1024][3]
#define TAB_FLOATS (NCELL * 3)
#define TAB_BYTES (TAB_FLOATS * 4)
#define ST_OFF TAB_BYTES
#define ST_BYTES (NCELL * 4)
#define PART_OFF (TAB_BYTES + ST_BYTES)

// ---------------------------------------------------------------------------
// Build the r-tables: cell c holds {St, Sg, Sl} at r = c/TSCALE, plus a
// packed St-only copy for EMODE blocks' lighter staging.
__global__ __launch_bounds__(256)
void tfl_tabgen(const float* __restrict__ p1, const float* __restrict__ pb1,
                const float* __restrict__ p2, float* __restrict__ tab,
                float* __restrict__ stTab) {
  const int c = blockIdx.x * 256 + threadIdx.x;
  if (c >= NCELL) return;
  const float r = (float)c * (RMAX / (float)NCELL);
  float St = 0.f, Sg = 0.f, Sl = 0.f;
  for (int h = 0; h < H_DIM; ++h) {
    float p1h = p1[h], P2h = p2[h];
    float arg = TWO_LOG2E * fmaf(r, p1h, pb1[h]);
    float y = __builtin_amdgcn_exp2f(arg);
    float u = __builtin_amdgcn_rcpf(y + 1.0f);
    float t = fmaf(-2.0f, u, 1.0f);            // tanh
    float dd = fmaf(-u, u, u);                 // sech^2 / 4
    St = fmaf(t, P2h, St);
    Sg = fmaf(dd, 4.0f * p1h * P2h, Sg);       // dPhi
    Sl = fmaf(t * dd, -8.0f * p1h * p1h * P2h, Sl);  // d2Phi
  }
  tab[3 * c + 0] = St;
  tab[3 * c + 1] = Sg;
  tab[3 * c + 2] = Sl;
  stTab[c] = St;
}

// ---------------------------------------------------------------------------
// Main: 1024 blocks = 32 jobs x 32 rowgroups(16 rows). 512 threads:
// 32 threads per row, each thread owns 16 j's. Single float3 table (12B
// stride -> gcd(3,32)=1 -> random gathers spread over all 32 banks; round-3
// lesson: an 8B-stride float2 table aliases to even banks only, ~2x
// conflicts). Mode-specialized READS on the same table (E telescoped):
//   DRIFT (l=1..6): ds_read2_b32 {Sg,Sl} at 3ki+1,3ki+2; skip St & Vi;
//                   3-var reduce.
//   L0    (l==0)  : full b96 path, identical to round-2 (4-var reduce).
//   EMODE (l==7)  : stage only packed 8KB St table (aliased); 1-dword
//                   gather; 1-var reduce.
// No cross-block sync (round-1/3 lesson: agent-scope release/acquire emits
// buffer_wbl2/inv -> L2 maintenance storm costing more than a launch gap).
__global__ __launch_bounds__(512)
void tfl_main8(const float* __restrict__ data, const float* __restrict__ tsnap,
               const float* __restrict__ W1, const float* __restrict__ b1,
               const float* __restrict__ w2, const float* __restrict__ tab,
               const float* __restrict__ stTab, double* __restrict__ partials) {
  const int jb = blockIdx.x >> 5;
  const int rb = blockIdx.x & 31;
  const bool emode = (jb >= N_STEPS);
  const int m = emode ? (jb - N_STEPS) : jb / (L_DIM - 1);
  const int l = emode ? (L_DIM - 1) : jb % (L_DIM - 1);
  const bool l0 = (!emode && l == 0);
  const float* X = data + (size_t)(m * L_DIM + l) * (N_PART * 2);

  __shared__ __align__(16) float sTab[TAB_FLOATS];  // 24 KB (EMODE: St-only view)
  __shared__ __align__(16) float Xs[N_PART * 2];    // 4 KB
  __shared__ double sred[8][3];

  const int tid = threadIdx.x;
  if (tid < 256) ((float4*)Xs)[tid] = ((const float4*)X)[tid];
  if (!emode) {
#pragma unroll
    for (int q = 0; q < 3; ++q)
      ((float4*)sTab)[tid + 512 * q] = ((const float4*)tab)[tid + 512 * q];
  } else {
    ((float4*)sTab)[tid] = ((const float4*)stTab)[tid];   // 8 KB packed St
  }
  __syncthreads();

  const int wv = tid >> 6;
  const int ln = tid & 63;
  const int g = ln & 31;               // j-group id / h id (32 lanes per row)
  const int row = rb * 16 + (tid >> 5);
  const float xi0 = Xs[2 * row], xi1 = Xs[2 * row + 1];
  const float invN = 1.0f / N_PART;
  const float invN2 = invN * invN;
  const float rs0 = __builtin_amdgcn_rsqf(1e-20f);
  const float2* Xs2 = (const float2*)Xs;

  float bJd = 0.f, bLap = 0.f, bE = 0.f;       // this wave's 2-row partials

  if (!emode && !l0) {
    // ------- DRIFT: {Sg,Sl} 2-dword gather, no St, no Vi, 3-var reduce ----
    float aGx = 0.f, aGy = 0.f, aLw = 0.f;
#pragma unroll 4
    for (int kk = 0; kk < 16; ++kk) {
      const int j = g + 32 * kk;
      float2 xj = Xs2[j];
      float dx = xi0 - xj.x, dy = xi1 - xj.y;
      float sq = fmaxf(fmaf(dx, dx, dy * dy), 1e-20f);
      float rs = __builtin_amdgcn_rsqf(sq);
      float r = sq * rs;
      int ki = (int)fmaf(r, TSCALE, 0.5f);
      ki = min(ki, NCELL - 1);
      const int b = 3 * ki;
      float Sgv = sTab[b + 1], Slv = sTab[b + 2];
      float tg = Sgv * rs;                      // dPhi / r
      aGx = fmaf(dx, tg, aGx);
      aGy = fmaf(dy, tg, aGy);
      aLw += tg + Slv;                          // d2Phi + dPhi/r (incl diag)
    }
    float gVx, gVy, lapV;
    {
      float w10 = W1[g], w11 = W1[H_DIM + g], w2h = w2[g];
      float arg = TWO_LOG2E * fmaf(xi0, w10, fmaf(xi1, w11, b1[g]));
      float y = __builtin_amdgcn_exp2f(arg);
      float u = __builtin_amdgcn_rcpf(y + 1.0f);
      float t = fmaf(-2.0f, u, 1.0f);
      float dd = fmaf(-u, u, u);
      float g4 = 4.0f * dd * w2h;
      gVx = g4 * w10;
      gVy = g4 * w11;
      lapV = t * dd * (-8.0f * w2h) * fmaf(w10, w10, w11 * w11);
    }
    float gx = fmaf(aGx, invN, gVx);
    float gy = fmaf(aGy, invN, gVy);
    float lw = fmaf(aLw, invN, lapV);
#pragma unroll
    for (int sh = 1; sh < 32; sh <<= 1) {
      gx += __shfl_xor(gx, sh);
      gy += __shfl_xor(gy, sh);
      lw += __shfl_xor(lw, sh);
    }
    lw -= fmaf(sTab[1], rs0, sTab[2]) * invN;   // remove diagonal lap term
    float cJd = fmaf(gx, gx, gy * gy);
    cJd += __shfl_xor(cJd, 32);
    lw += __shfl_xor(lw, 32);
    bJd = cJd; bLap = lw;
  } else if (l0) {
    // ------- L0: full path (identical ops to round-2 unified kernel) ------
    float aSt = 0.f, aGx = 0.f, aGy = 0.f, aLw = 0.f;
#pragma unroll 4
    for (int kk = 0; kk < 16; ++kk) {
      const int j = g + 32 * kk;
      float2 xj = Xs2[j];
      float dx = xi0 - xj.x, dy = xi1 - xj.y;
      float sq = fmaxf(fmaf(dx, dx, dy * dy), 1e-20f);
      float rs = __builtin_amdgcn_rsqf(sq);
      float r = sq * rs;
      int ki = (int)fmaf(r, TSCALE, 0.5f);
      ki = min(ki, NCELL - 1);
      const int b = 3 * ki;
      float Stv = sTab[b], Sgv = sTab[b + 1], Slv = sTab[b + 2];
      float tg = Sgv * rs;
      aSt += Stv;
      aGx = fmaf(dx, tg, aGx);
      aGy = fmaf(dy, tg, aGy);
      aLw += tg + Slv;
    }
    float Vi, gVx, gVy, lapV;
    {
      float w10 = W1[g], w11 = W1[H_DIM + g], w2h = w2[g];
      float arg = TWO_LOG2E * fmaf(xi0, w10, fmaf(xi1, w11, b1[g]));
      float y = __builtin_amdgcn_exp2f(arg);
      float u = __builtin_amdgcn_rcpf(y + 1.0f);
      float t = fmaf(-2.0f, u, 1.0f);
      float dd = fmaf(-u, u, u);
      Vi = t * w2h;
      float g4 = 4.0f * dd * w2h;
      gVx = g4 * w10;
      gVy = g4 * w11;
      lapV = t * dd * (-8.0f * w2h) * fmaf(w10, w10, w11 * w11);
    }
    float eA = fmaf(aSt, invN2, Vi * invN);
    float gx = fmaf(aGx, invN, gVx);
    float gy = fmaf(aGy, invN, gVy);
    float lw = fmaf(aLw, invN, lapV);
#pragma unroll
    for (int sh = 1; sh < 32; sh <<= 1) {
      eA += __shfl_xor(eA, sh);
      gx += __shfl_xor(gx, sh);
      gy += __shfl_xor(gy, sh);
      lw += __shfl_xor(lw, sh);
    }
    eA -= sTab[0] * invN2;
    lw -= fmaf(sTab[1], rs0, sTab[2]) * invN;
    float cJd = fmaf(gx, gx, gy * gy);
    cJd += __shfl_xor(cJd, 32);
    lw += __shfl_xor(lw, 32);
    eA += __shfl_xor(eA, 32);
    bJd = cJd; bLap = lw; bE = eA;
  } else {
    // ------- EMODE: packed St view, 1-dword gather, 1-var reduce ----------
    float aSt = 0.f;
#pragma unroll 4
    for (int kk = 0; kk < 16; ++kk) {
      const int j = g + 32 * kk;
      float2 xj = Xs2[j];
      float dx = xi0 - xj.x, dy = xi1 - xj.y;
      float sq = fmaxf(fmaf(dx, dx, dy * dy), 1e-20f);
      float rs = __builtin_amdgcn_rsqf(sq);
      float r = sq * rs;
      int ki = (int)fmaf(r, TSCALE, 0.5f);
      ki = min(ki, NCELL - 1);
      aSt += sTab[ki];                          // packed St
    }
    float Vi;
    {
      float w10 = W1[g], w11 = W1[H_DIM + g], w2h = w2[g];
      float arg = TWO_LOG2E * fmaf(xi0, w10, fmaf(xi1, w11, b1[g]));
      float y = __builtin_amdgcn_exp2f(arg);
      float u = __builtin_amdgcn_rcpf(y + 1.0f);
      float t = fmaf(-2.0f, u, 1.0f);
      Vi = t * w2h;
    }
    float eA = fmaf(aSt, invN2, Vi * invN);
#pragma unroll
    for (int sh = 1; sh < 32; sh <<= 1) eA += __shfl_xor(eA, sh);
    eA -= sTab[0] * invN2;                      // remove diagonal Phi term
    eA += __shfl_xor(eA, 32);
    bE = eA;
  }

  // ----- per-wave partials -> block partial -> global store -----
  if (ln == 0) { sred[wv][0] = bJd; sred[wv][1] = bLap; sred[wv][2] = bE; }
  __syncthreads();
  if (tid == 0) {
    double sJd = 0, sLap = 0, sE = 0;
    for (int w = 0; w < 8; ++w) {
      sJd += sred[w][0]; sLap += sred[w][1]; sE += sred[w][2];
    }
    const double dN = 1.0 / N_PART;
    double j0 = 0.0, j1 = 0.0, j2 = 0.0;
    if (emode) {
      j2 = sE;                                  // +E(m, L-1) telescoped
    } else {
      double dt = (double)(tsnap[l + 1] - tsnap[l]);
      j0 = dt * dN * sJd;                       // J_diss partial
      j1 = dt * 0.01 * dN * sLap;               // J_diff partial
      if (l == 0) j2 = -sE;                     // -E(m, 0) telescoped
    }
    partials[(size_t)blockIdx.x * 3 + 0] = j0;
    partials[(size_t)blockIdx.x * 3 + 1] = j1;
    partials[(size_t)blockIdx.x * 3 + 2] = j2;
  }
}

// ---------------------------------------------------------------------------
// 1 block, 512 threads: each thread sums 2 partial triplets, then a 6-step
// 64-lane shuffle reduce + 8-wave LDS combine (one barrier).
__global__ __launch_bounds__(512)
void tfl_finalize(const double* __restrict__ partials, float* __restrict__ out) {
  __shared__ double sred[8][3];
  const int tid = threadIdx.x;
  const int wv = tid >> 6;
  const int ln = tid & 63;
  const double* pa = partials + (size_t)tid * 3;
  const double* pb = partials + (size_t)(tid + 512) * 3;
  double t0 = pa[0] + pb[0];
  double t1 = pa[1] + pb[1];
  double t2 = pa[2] + pb[2];
#pragma unroll
  for (int sh = 1; sh < 64; sh <<= 1) {
    t0 += __shfl_xor(t0, sh);
    t1 += __shfl_xor(t1, sh);
    t2 += __shfl_xor(t2, sh);
  }
  if (ln == 0) { sred[wv][0] = t0; sred[wv][1] = t1; sred[wv][2] = t2; }
  __syncthreads();
  if (tid == 0) {
    double s0 = 0, s1 = 0, s2 = 0;
    for (int w = 0; w < 8; ++w) {
      s0 += sred[w][0]; s1 += sred[w][1]; s2 += sred[w][2];
    }
    double r = (s0 + s1 - 2.0 * s2) / (double)N_STEPS;
    out[0] = (float)(r * r);
  }
}

// ---------------------------------------------------------------------------
extern "C" void kernel_launch(void* const* d_in, const int* in_sizes, int n_in,
                              void* d_out, int out_size, void* d_ws, size_t ws_size,
                              hipStream_t stream) {
  (void)in_sizes; (void)n_in; (void)out_size; (void)ws_size;
  const float* data  = (const float*)d_in[0];
  const float* tsnap = (const float*)d_in[1];
  const float* W1    = (const float*)d_in[2];
  const float* b1    = (const float*)d_in[3];
  const float* w2    = (const float*)d_in[4];
  // d_in[5] = b2 (cancels in telescoped dE)
  const float* p1    = (const float*)d_in[6];
  const float* pb1   = (const float*)d_in[7];
  const float* p2    = (const float*)d_in[8];
  // d_in[9] = pb2 (cancels in telescoped dE)
  float* tab = (float*)d_ws;
  float* stTab = (float*)((char*)d_ws + ST_OFF);
  double* partials = (double*)((char*)d_ws + PART_OFF);
  float* out = (float*)d_out;

  hipLaunchKernelGGL(tfl_tabgen, dim3(NCELL / 256), dim3(256), 0, stream,
                     p1, pb1, p2, tab, stTab);
  hipLaunchKernelGGL(tfl_main8, dim3(NBLK), dim3(512), 0, stream,
                     data, tsnap, W1, b1, w2, tab, stTab, partials);
  hipLaunchKernelGGL(tfl_finalize, dim3(1), dim3(512), 0, stream, partials, out);
}